// Round 14
// baseline (50.757 us; speedup 1.0000x reference)
//
#include <hip/hip_runtime.h>

#define N_ROWS   1024
#define D_DIM    128
#define C_CLS    50000
#define C_PAD    50048
#define NCT64    782        // 50048/64 column tiles (64 cols each)
#define NG       128        // ct groups; 782 = 6*128 + 14
#define NPART    256        // partials per row = NG * 2 col-halves
#define S_SCALE  30.0f
#define M_MARGIN 0.35f
#define EXP2_SCALE 43.2808512266689f    // 30 * log2(e)  (folded into fhat)
#define EXP2M      15.1482979293341f    // M_MARGIN * EXP2_SCALE
#define LN2        0.6931471805599453f

typedef short s8v __attribute__((ext_vector_type(8)));   // 8 x bf16 bits (4 VGPRs)
typedef float f4v __attribute__((ext_vector_type(4)));

__device__ inline unsigned short f2bf(float f) {
    unsigned u = __float_as_uint(f);
    u += 0x7FFF + ((u >> 16) & 1);      // round-to-nearest-even (inputs are finite)
    return (unsigned short)(u >> 16);
}
__device__ inline float bf2f(unsigned short h) {
    return __uint_as_float(((unsigned)h) << 16);
}
__device__ inline void load_lds16(const char* src, unsigned char* lds) {
    __builtin_amdgcn_global_load_lds(
        (const __attribute__((address_space(1))) void*)src,
        (__attribute__((address_space(3))) void*)lds, 16, 0, 0);
}

// ---------------------------------------------------------------------------
// Row-normalize, float4 (16B/lane), 2 rows per wave (half-wave per row).
// rows [0,C_PAD): weight -> what, unit norm (rows >= C_CLS zeroed).
// rows [C_PAD,+N_ROWS): feature -> fhat, norm SCALED by EXP2_SCALE so the
// GEMM's MFMA output is directly in exp2 units. Block 0 also zeroes the
// finalize completion counter (re-zeroed every call -> replay-deterministic).
// ---------------------------------------------------------------------------
__global__ void norm_rows_fused(const float* __restrict__ weight,
                                const float* __restrict__ feature,
                                unsigned short* __restrict__ what,
                                unsigned short* __restrict__ fhat,
                                int* __restrict__ ctr) {
    if (blockIdx.x == 0 && threadIdx.x == 0) *ctr = 0;
    int wid = threadIdx.x >> 6, lane = threadIdx.x & 63;
    int half = lane >> 5, l32 = lane & 31;
    int r = blockIdx.x * 8 + wid * 2 + half;

    const float* src;
    unsigned short* dst;
    int srcRow, valid;
    float scale;
    if (r < C_PAD) {
        src = weight; dst = what; srcRow = r; valid = (r < C_CLS); scale = 1.0f;
    } else {
        src = feature; dst = fhat; srcRow = r - C_PAD; valid = 1; scale = EXP2_SCALE;
    }
    float4 v = make_float4(0.f, 0.f, 0.f, 0.f);
    if (valid) v = ((const float4*)src)[(size_t)srcRow * 32 + l32];
    float ss = v.x * v.x + v.y * v.y + v.z * v.z + v.w * v.w;
    #pragma unroll
    for (int s = 1; s < 32; s <<= 1) ss += __shfl_xor(ss, s, 32);
    float inv = valid ? scale / fmaxf(sqrtf(ss), 1e-8f) : 0.f;
    ushort4 o;
    o.x = f2bf(v.x * inv); o.y = f2bf(v.y * inv);
    o.z = f2bf(v.z * inv); o.w = f2bf(v.w * inv);
    ((ushort4*)dst)[(size_t)srcRow * 32 + l32] = o;
}

// ---------------------------------------------------------------------------
// ct-loop GEMM+exp  (round-11 structure, best measured: total 36.0us).
// Block (g, rt): 128 rows x 64 cols per tile, tiles ct = g + 128*t (6-7).
// LDS = 32KB: A (32KB) bounces through it in the prologue -> registers; then
// TWO 16KB B buffers. Per tile: __syncthreads() -> issue stage(t+1) ->
// compute tile t (stage latency hides under compute). XOR swizzle on the
// GLOBAL source (rule #21), linear LDS dest, swizzled ds_read. Wave layout
// 2x2. acc already exp2-scaled -> esum += exp2(acc) directly.
// SESSION RULE: never request >=4 waves/EU in __launch_bounds__ -- it coerces
// the allocator to 64 arch VGPRs and spills (r10/r12: 45-49MB scratch,
// MfmaUtil ~9%). (256,3) allocates ~84 VGPR spill-free; HW still resides
// 4 blocks/CU (84 <= 128-step, LDS 32KB allows 5).
// ---------------------------------------------------------------------------
__global__ __launch_bounds__(256, 3)
void gemm_exp_kernel(const short* __restrict__ fhat,
                     const short* __restrict__ what,
                     float* __restrict__ part2) {
    __shared__ __align__(16) unsigned char smem[32768];   // 2 x 16KB B buffers
    const int g   = blockIdx.x;           // ct group, 0..127
    const int rt  = blockIdx.y;           // row tile, 0..7
    const int tid = threadIdx.x;
    const int wid = tid >> 6;
    const int lane = tid & 63;
    const int lrow = lane & 15;
    const int kgrp = lane >> 4;
    const int wrow = wid >> 1;            // row half (64 rows)
    const int wcol = wid & 1;             // col half (32 cols)
    const int nt = (g < 14) ? 7 : 6;      // tiles in this group (782 = 6*128+14)

    const char* aSrc  = (const char*)fhat + (size_t)rt * 32768;
    const char* bBase = (const char*)what;

    // ---- prologue: A tile (32KB) -> whole smem, then A -> registers ----
    #pragma unroll
    for (int i = 0; i < 8; i++) {
        int o = wid * 8192 + i * 1024 + lane * 16;
        int s = o ^ (((o >> 8) & 7) << 4);      // source pre-swizzle (involution)
        load_lds16(aSrc + s, smem + o);
    }
    __syncthreads();

    s8v afr[4][4];                        // wave rows: wrow*64 + m*16 + lrow
    #pragma unroll
    for (int kk = 0; kk < 4; kk++)
        #pragma unroll
        for (int m = 0; m < 4; m++) {
            int row = wrow * 64 + m * 16 + lrow;
            int b = (row * 256 + kk * 64 + kgrp * 16) ^ ((row & 7) << 4);
            afr[kk][m] = *(const s8v*)(smem + b);
        }
    __syncthreads();                      // afr reads retired; smem reusable

    // ---- stage B(t=0) -> buf0 ----
    #pragma unroll
    for (int i = 0; i < 4; i++) {
        int o = wid * 4096 + i * 1024 + lane * 16;
        int s = o ^ (((o >> 8) & 7) << 4);
        load_lds16(bBase + (size_t)g * 16384 + s, smem + o);
    }

    float esum[4][4];
    #pragma unroll
    for (int m = 0; m < 4; m++)
        #pragma unroll
        for (int j = 0; j < 4; j++) esum[m][j] = 0.f;

    for (int t = 0; t < nt; ++t) {
        const int ct = g + 128 * t;
        // vmcnt(0)+lgkmcnt(0)+barrier: stage(t) landed; buf[(t+1)&1]'s
        // readers (tile t-1) all done -> safe to overwrite.
        __syncthreads();

        if (t + 1 < nt) {                 // issue stage(t+1) BEFORE compute
            const char* src = bBase + (size_t)(ct + 128) * 16384;
            unsigned char* dstb = smem + ((t + 1) & 1) * 16384;
            #pragma unroll
            for (int i = 0; i < 4; i++) {
                int o = wid * 4096 + i * 1024 + lane * 16;
                int s = o ^ (((o >> 8) & 7) << 4);
                load_lds16(src + s, dstb + o);
            }
        }

        const unsigned char* bb = smem + (t & 1) * 16384;
        f4v acc[4][2];
        f4v zero = {0.f, 0.f, 0.f, 0.f};
        #pragma unroll
        for (int m = 0; m < 4; m++) { acc[m][0] = zero; acc[m][1] = zero; }

        #pragma unroll
        for (int kk = 0; kk < 4; kk++) {
            s8v bfr[2];
            #pragma unroll
            for (int n = 0; n < 2; n++) {
                int row = wcol * 32 + n * 16 + lrow;   // B^T row = output col
                int b = (row * 256 + kk * 64 + kgrp * 16) ^ ((row & 7) << 4);
                bfr[n] = *(const s8v*)(bb + b);
            }
            #pragma unroll
            for (int m = 0; m < 4; m++) {
                acc[m][0] = __builtin_amdgcn_mfma_f32_16x16x32_bf16(
                    afr[kk][m], bfr[0], acc[m][0], 0, 0, 0);
                acc[m][1] = __builtin_amdgcn_mfma_f32_16x16x32_bf16(
                    afr[kk][m], bfr[1], acc[m][1], 0, 0, 0);
            }
        }

        if (ct != NCT64 - 1) {            // fast path: all 32 cols valid
            #pragma unroll
            for (int m = 0; m < 4; m++)
                #pragma unroll
                for (int n = 0; n < 2; n++)
                    #pragma unroll
                    for (int j = 0; j < 4; j++)
                        esum[m][j] += __builtin_amdgcn_exp2f(acc[m][n][j]);
        } else {                          // tail tile: mask padded cols
            #pragma unroll
            for (int n = 0; n < 2; n++) {
                int gc = ct * 64 + wcol * 32 + n * 16 + lrow;
                #pragma unroll
                for (int m = 0; m < 4; m++)
                    #pragma unroll
                    for (int j = 0; j < 4; j++)
                        if (gc < C_CLS)
                            esum[m][j] += __builtin_amdgcn_exp2f(acc[m][n][j]);
            }
        }
    }

    // ---- epilogue: reduce over the wave's 16 col-lanes, direct write ----
    #pragma unroll
    for (int m = 0; m < 4; m++)
        #pragma unroll
        for (int j = 0; j < 4; j++) {
            float v = esum[m][j];
            v += __shfl_xor(v, 1, 64);
            v += __shfl_xor(v, 2, 64);
            v += __shfl_xor(v, 4, 64);
            v += __shfl_xor(v, 8, 64);
            if (lrow == 0) {
                int row = rt * 128 + wrow * 64 + m * 16 + kgrp * 4 + j;
                part2[(size_t)row * NPART + g * 2 + wcol] = v;
            }
        }
}

// ---------------------------------------------------------------------------
// Fused finalize + final reduce. One wave per row (4 rows/block, 256 blocks):
// S_n = sum of 256 partials (4/lane); cys = fp32 dot of the SAME bf16 vectors
// = EXP2_SCALE*cos_y; Sp = S - exp2(cys) + exp2(cys - EXP2M);
// rowval[n] = (ln(Sp) - LN2*(cys-EXP2M))/N + 0.005*||f_n - w_y||^2.
// Then: device-scope release fence + atomic counter; the LAST block re-reads
// all 1024 rowvals in a FIXED order and writes the final scalar ->
// deterministic regardless of which block is last. ctr is zeroed by
// norm_rows_fused every call -> graph-replay safe.
// ---------------------------------------------------------------------------
__global__ void finalize_rows_kernel(const float* __restrict__ part2,
                                     const unsigned short* __restrict__ fhat,
                                     const unsigned short* __restrict__ what,
                                     const float* __restrict__ feature,
                                     const float* __restrict__ weight,
                                     const int* __restrict__ label,
                                     float* __restrict__ rowval,
                                     int* __restrict__ ctr,
                                     float* __restrict__ out) {
    __shared__ float sbuf[4];
    __shared__ int lastFlag;
    int wid = threadIdx.x >> 6, lane = threadIdx.x & 63;
    int n = blockIdx.x * 4 + wid;
    int y = label[n];

    const float* p = part2 + (size_t)n * NPART;
    float S = p[lane] + p[64 + lane] + p[128 + lane] + p[192 + lane];

    float2 f2 = ((const float2*)feature)[(size_t)n * 64 + lane];
    float2 w2 = ((const float2*)weight)[(size_t)y * 64 + lane];
    float dx = f2.x - w2.x, dy = f2.y - w2.y;
    float cl = dx * dx + dy * dy;

    ushort2 fh = ((const ushort2*)fhat)[(size_t)n * 64 + lane];
    ushort2 wh = ((const ushort2*)what)[(size_t)y * 64 + lane];
    float cys = bf2f(fh.x) * bf2f(wh.x) + bf2f(fh.y) * bf2f(wh.y);

    #pragma unroll
    for (int s = 1; s < 64; s <<= 1) {
        S   += __shfl_xor(S, s, 64);
        cl  += __shfl_xor(cl, s, 64);
        cys += __shfl_xor(cys, s, 64);
    }
    if (lane == 0) {
        float t2 = cys - EXP2M;
        float Sp = S - __builtin_amdgcn_exp2f(cys) + __builtin_amdgcn_exp2f(t2);
        rowval[n] = (logf(Sp) - LN2 * t2) * (1.0f / (float)N_ROWS) + 0.005f * cl;
    }

    // ---- completion detection: last block performs the final reduction ----
    __threadfence();                      // release rowval writes device-wide
    if (threadIdx.x == 0) {
        int old = atomicAdd(ctr, 1);      // device-scope by default
        lastFlag = (old == (N_ROWS / 4) - 1);
    }
    __syncthreads();
    if (!lastFlag) return;

    int t = threadIdx.x;                  // 256 threads, fixed-order sum
    float v = rowval[t] + rowval[t + 256] + rowval[t + 512] + rowval[t + 768];
    #pragma unroll
    for (int s = 1; s < 64; s <<= 1) v += __shfl_xor(v, s, 64);
    if ((t & 63) == 0) sbuf[t >> 6] = v;
    __syncthreads();
    if (t == 0) out[0] = sbuf[0] + sbuf[1] + sbuf[2] + sbuf[3];
}

// ---------------------------------------------------------------------------
extern "C" void kernel_launch(void* const* d_in, const int* in_sizes, int n_in,
                              void* d_out, int out_size, void* d_ws, size_t ws_size,
                              hipStream_t stream) {
    const float* feature = (const float*)d_in[0];
    const float* weight  = (const float*)d_in[1];
    const int*   label   = (const int*)d_in[2];

    // Workspace layout (bytes):
    //   what   [0,        12812288)  : 50048*128*2
    //   fhat   [12812288, 13074432)  : 1024*128*2
    //   part2  [13074432, 14123008)  : 1024*256*4
    //   rowval [14123008, 14127104)  : 1024*4
    //   ctr    [14127104, 14127108)  : 1 int
    const size_t WS_NEEDED = 14127108;
    if (ws_size < WS_NEEDED) return;   // defensive: visible failure, not OOB writes

    char* ws = (char*)d_ws;
    unsigned short* what = (unsigned short*)ws;
    unsigned short* fhat = (unsigned short*)(ws + 12812288);
    float*         part2 = (float*)(ws + 13074432);
    float*        rowval = (float*)(ws + 14123008);
    int*             ctr = (int*)(ws + 14127104);

    norm_rows_fused<<<dim3((C_PAD + N_ROWS) / 8), 256, 0, stream>>>(weight, feature, what, fhat, ctr);
    gemm_exp_kernel<<<dim3(NG, 8), 256, 0, stream>>>((const short*)fhat, (const short*)what, part2);
    finalize_rows_kernel<<<dim3(N_ROWS / 4), 256, 0, stream>>>(part2, fhat, what, feature, weight,
                                                               label, rowval, ctr, (float*)d_out);
}

// Round 15
// 35.259 us; speedup vs baseline: 1.4395x; 1.4395x over previous
//
#include <hip/hip_runtime.h>

#define N_ROWS   1024
#define D_DIM    128
#define C_CLS    50000
#define C_PAD    50048
#define NCT64    782        // 50048/64 column tiles (64 cols each)
#define NG       128        // ct groups; 782 = 6*128 + 14
#define NPART    256        // partials per row = NG * 2 col-halves
#define S_SCALE  30.0f
#define M_MARGIN 0.35f
#define EXP2_SCALE 43.2808512266689f    // 30 * log2(e)  (folded into fhat)
#define EXP2M      15.1482979293341f    // M_MARGIN * EXP2_SCALE
#define LN2        0.6931471805599453f

typedef short s8v __attribute__((ext_vector_type(8)));   // 8 x bf16 bits (4 VGPRs)
typedef float f4v __attribute__((ext_vector_type(4)));

__device__ inline unsigned short f2bf(float f) {
    unsigned u = __float_as_uint(f);
    u += 0x7FFF + ((u >> 16) & 1);      // round-to-nearest-even (inputs are finite)
    return (unsigned short)(u >> 16);
}
__device__ inline float bf2f(unsigned short h) {
    return __uint_as_float(((unsigned)h) << 16);
}
__device__ inline void load_lds16(const char* src, unsigned char* lds) {
    __builtin_amdgcn_global_load_lds(
        (const __attribute__((address_space(1))) void*)src,
        (__attribute__((address_space(3))) void*)lds, 16, 0, 0);
}

// ---------------------------------------------------------------------------
// Row-normalize with XCD-MATCHED placement for weight rows.
// Gemm reads B tile ct (rows [ct*64, +64)) only from blocks with g = ct%128,
// which land on XCD (g + 128*rt) % 8 = ct % 8 (round-robin heuristic). So the
// 8 norm blocks that WRITE tile ct are remapped to hardware blockIdx B with
// B % 8 == ct % 8 -> the tile's 16KB lands in the READER's L2, making the
// gemm's cold-pass B reads local-L2 hits instead of remote-L2/L3.
// Mapping: B = q*8 + x (x = XCD), c2 = q>>3, j = q&7, ct = x + 8*c2,
// rows [ct*64 + j*8, +8). Bijective over ct < 782; x in {6,7} & c2 == 97
// are idle (ct would be 782/783). Feature rows: natural mapping, blocks
// [6272, 6400); fhat is read by all XCDs anyway (no preferred placement).
// float4 loads (16B/lane), 2 rows/wave. fhat norm scaled by EXP2_SCALE.
// ---------------------------------------------------------------------------
__global__ void norm_rows_fused(const float* __restrict__ weight,
                                const float* __restrict__ feature,
                                unsigned short* __restrict__ what,
                                unsigned short* __restrict__ fhat) {
    int wid = threadIdx.x >> 6, lane = threadIdx.x & 63;
    int half = lane >> 5, l32 = lane & 31;
    int B = blockIdx.x;

    const float* src;
    unsigned short* dst;
    int rowBase, isW;
    float scale;
    if (B < 6272) {                       // weight rows, XCD-matched
        int x = B & 7, q = B >> 3;
        int ct = x + 8 * (q >> 3);
        if (ct >= NCT64) return;          // idle tail (x in {6,7}, c2 == 97)
        rowBase = ct * 64 + (q & 7) * 8;
        src = weight; dst = what; scale = 1.0f; isW = 1;
    } else {                              // feature rows, natural
        rowBase = (B - 6272) * 8;
        src = feature; dst = fhat; scale = EXP2_SCALE; isW = 0;
    }

    int srcRow = rowBase + wid * 2 + half;
    int valid = isW ? (srcRow < C_CLS) : 1;

    float4 v = make_float4(0.f, 0.f, 0.f, 0.f);
    if (valid) v = ((const float4*)src)[(size_t)srcRow * 32 + l32];
    float ss = v.x * v.x + v.y * v.y + v.z * v.z + v.w * v.w;
    #pragma unroll
    for (int s = 1; s < 32; s <<= 1) ss += __shfl_xor(ss, s, 32);
    float inv = valid ? scale / fmaxf(sqrtf(ss), 1e-8f) : 0.f;
    ushort4 o;
    o.x = f2bf(v.x * inv); o.y = f2bf(v.y * inv);
    o.z = f2bf(v.z * inv); o.w = f2bf(v.w * inv);
    ((ushort4*)dst)[(size_t)srcRow * 32 + l32] = o;
}

// ---------------------------------------------------------------------------
// ct-loop GEMM+exp (round-11 sync structure, best measured 36.0us total).
// Block (g, rt): 128 rows x 64 cols per tile, tiles ct = g + 128*t (6-7).
// LDS 32KB: A bounces through it in the prologue -> registers; then TWO
// 16KB B buffers. Per tile: __syncthreads() -> issue stage(t+1) -> compute.
// XOR swizzle on the GLOBAL source (rule #21), linear LDS dest.
// VALU cuts vs r11 (warm loop is VALU-issue-bound per r9 PMC):
//  (1) zero-C trick: first k-step uses a single 4-reg FZERO as MFMA C ->
//      kills 32 acc-init v_movs per tile per wave (~2us/chip).
//  (2) B ds_read addresses hoisted to vb[2][4] (loop-invariant) -> kills
//      per-tile swizzle arithmetic (~1.5us/chip).
// SESSION RULE: never request >=4 waves/EU (r10/r12: allocator clamps to 64
// VGPR and spills 45-49MB scratch). (256,3) = ~84 VGPR spill-free; HW still
// resides 4 blocks/CU since 84+acc <= 128-step and LDS 32KB allows 5.
// ---------------------------------------------------------------------------
__global__ __launch_bounds__(256, 3)
void gemm_exp_kernel(const short* __restrict__ fhat,
                     const short* __restrict__ what,
                     float* __restrict__ part2) {
    __shared__ __align__(16) unsigned char smem[32768];   // 2 x 16KB B buffers
    const int g   = blockIdx.x;           // ct group, 0..127
    const int rt  = blockIdx.y;           // row tile, 0..7
    const int tid = threadIdx.x;
    const int wid = tid >> 6;
    const int lane = tid & 63;
    const int lrow = lane & 15;
    const int kgrp = lane >> 4;
    const int wrow = wid >> 1;            // row half (64 rows)
    const int wcol = wid & 1;             // col half (32 cols)
    const int nt = (g < 14) ? 7 : 6;      // tiles in this group (782 = 6*128+14)

    const char* aSrc  = (const char*)fhat + (size_t)rt * 32768;
    const char* bBase = (const char*)what;

    // ---- prologue: A tile (32KB) -> whole smem, then A -> registers ----
    #pragma unroll
    for (int i = 0; i < 8; i++) {
        int o = wid * 8192 + i * 1024 + lane * 16;
        int s = o ^ (((o >> 8) & 7) << 4);      // source pre-swizzle (involution)
        load_lds16(aSrc + s, smem + o);
    }
    __syncthreads();

    s8v afr[4][4];                        // wave rows: wrow*64 + m*16 + lrow
    #pragma unroll
    for (int kk = 0; kk < 4; kk++)
        #pragma unroll
        for (int m = 0; m < 4; m++) {
            int row = wrow * 64 + m * 16 + lrow;
            int b = (row * 256 + kk * 64 + kgrp * 16) ^ ((row & 7) << 4);
            afr[kk][m] = *(const s8v*)(smem + b);
        }
    __syncthreads();                      // afr reads retired; smem reusable

    // ---- loop-invariant B ds_read addresses (VALU cut #2) ----
    int vb[2][4];
    #pragma unroll
    for (int n = 0; n < 2; n++)
        #pragma unroll
        for (int kk = 0; kk < 4; kk++) {
            int row = wcol * 32 + n * 16 + lrow;   // B^T row = output col
            vb[n][kk] = (row * 256 + kk * 64 + kgrp * 16) ^ ((row & 7) << 4);
        }

    // ---- stage B(t=0) -> buf0 ----
    #pragma unroll
    for (int i = 0; i < 4; i++) {
        int o = wid * 4096 + i * 1024 + lane * 16;
        int s = o ^ (((o >> 8) & 7) << 4);
        load_lds16(bBase + (size_t)g * 16384 + s, smem + o);
    }

    float esum[4][4];
    #pragma unroll
    for (int m = 0; m < 4; m++)
        #pragma unroll
        for (int j = 0; j < 4; j++) esum[m][j] = 0.f;

    const f4v FZERO = {0.f, 0.f, 0.f, 0.f};   // one-time 4-reg zero (VALU cut #1)

    for (int t = 0; t < nt; ++t) {
        const int ct = g + 128 * t;
        // vmcnt(0)+lgkmcnt(0)+barrier: stage(t) landed; buf[(t+1)&1]'s
        // readers (tile t-1) all done -> safe to overwrite.
        __syncthreads();

        if (t + 1 < nt) {                 // issue stage(t+1) BEFORE compute
            const char* src = bBase + (size_t)(ct + 128) * 16384;
            unsigned char* dstb = smem + ((t + 1) & 1) * 16384;
            #pragma unroll
            for (int i = 0; i < 4; i++) {
                int o = wid * 4096 + i * 1024 + lane * 16;
                int s = o ^ (((o >> 8) & 7) << 4);
                load_lds16(src + s, dstb + o);
            }
        }

        const unsigned char* bb = smem + (t & 1) * 16384;
        f4v acc[4][2];

        {   // kk = 0: C = FZERO, no acc zero-init movs
            s8v b0 = *(const s8v*)(bb + vb[0][0]);
            s8v b1 = *(const s8v*)(bb + vb[1][0]);
            #pragma unroll
            for (int m = 0; m < 4; m++) {
                acc[m][0] = __builtin_amdgcn_mfma_f32_16x16x32_bf16(
                    afr[0][m], b0, FZERO, 0, 0, 0);
                acc[m][1] = __builtin_amdgcn_mfma_f32_16x16x32_bf16(
                    afr[0][m], b1, FZERO, 0, 0, 0);
            }
        }
        #pragma unroll
        for (int kk = 1; kk < 4; kk++) {
            s8v b0 = *(const s8v*)(bb + vb[0][kk]);
            s8v b1 = *(const s8v*)(bb + vb[1][kk]);
            #pragma unroll
            for (int m = 0; m < 4; m++) {
                acc[m][0] = __builtin_amdgcn_mfma_f32_16x16x32_bf16(
                    afr[kk][m], b0, acc[m][0], 0, 0, 0);
                acc[m][1] = __builtin_amdgcn_mfma_f32_16x16x32_bf16(
                    afr[kk][m], b1, acc[m][1], 0, 0, 0);
            }
        }

        if (ct != NCT64 - 1) {            // fast path: all 32 cols valid
            #pragma unroll
            for (int m = 0; m < 4; m++)
                #pragma unroll
                for (int n = 0; n < 2; n++)
                    #pragma unroll
                    for (int j = 0; j < 4; j++)
                        esum[m][j] += __builtin_amdgcn_exp2f(acc[m][n][j]);
        } else {                          // tail tile: mask padded cols
            #pragma unroll
            for (int n = 0; n < 2; n++) {
                int gc = ct * 64 + wcol * 32 + n * 16 + lrow;
                #pragma unroll
                for (int m = 0; m < 4; m++)
                    #pragma unroll
                    for (int j = 0; j < 4; j++)
                        if (gc < C_CLS)
                            esum[m][j] += __builtin_amdgcn_exp2f(acc[m][n][j]);
            }
        }
    }

    // ---- epilogue: reduce over the wave's 16 col-lanes, direct write ----
    #pragma unroll
    for (int m = 0; m < 4; m++)
        #pragma unroll
        for (int j = 0; j < 4; j++) {
            float v = esum[m][j];
            v += __shfl_xor(v, 1, 64);
            v += __shfl_xor(v, 2, 64);
            v += __shfl_xor(v, 4, 64);
            v += __shfl_xor(v, 8, 64);
            if (lrow == 0) {
                int row = rt * 128 + wrow * 64 + m * 16 + kgrp * 4 + j;
                part2[(size_t)row * NPART + g * 2 + wcol] = v;
            }
        }
}

// ---------------------------------------------------------------------------
// One wave per row: S_n = sum of 256 partials (4 per lane). cys = fp32 dot of
// the SAME bf16 vectors = EXP2_SCALE*cos_y, so Sp = S - exp2(cys) +
// exp2(cys - EXP2M); rowval[n] = (ln(Sp) - LN2*t2)/N + 0.005*||f_n - w_y||^2
// ---------------------------------------------------------------------------
__global__ void finalize_rows_kernel(const float* __restrict__ part2,
                                     const unsigned short* __restrict__ fhat,
                                     const unsigned short* __restrict__ what,
                                     const float* __restrict__ feature,
                                     const float* __restrict__ weight,
                                     const int* __restrict__ label,
                                     float* __restrict__ rowval) {
    int wid = threadIdx.x >> 6, lane = threadIdx.x & 63;
    int n = blockIdx.x * 4 + wid;
    int y = label[n];

    const float* p = part2 + (size_t)n * NPART;
    float S = p[lane] + p[64 + lane] + p[128 + lane] + p[192 + lane];

    float2 f2 = ((const float2*)feature)[(size_t)n * 64 + lane];
    float2 w2 = ((const float2*)weight)[(size_t)y * 64 + lane];
    float dx = f2.x - w2.x, dy = f2.y - w2.y;
    float cl = dx * dx + dy * dy;

    ushort2 fh = ((const ushort2*)fhat)[(size_t)n * 64 + lane];
    ushort2 wh = ((const ushort2*)what)[(size_t)y * 64 + lane];
    float cys = bf2f(fh.x) * bf2f(wh.x) + bf2f(fh.y) * bf2f(wh.y);

    #pragma unroll
    for (int s = 1; s < 64; s <<= 1) {
        S   += __shfl_xor(S, s, 64);
        cl  += __shfl_xor(cl, s, 64);
        cys += __shfl_xor(cys, s, 64);
    }
    if (lane == 0) {
        float t2 = cys - EXP2M;
        float Sp = S - __builtin_amdgcn_exp2f(cys) + __builtin_amdgcn_exp2f(t2);
        rowval[n] = (logf(Sp) - LN2 * t2) * (1.0f / (float)N_ROWS) + 0.005f * cl;
    }
}

__global__ void reduce_final_kernel(const float* __restrict__ rowval, float* __restrict__ out) {
    __shared__ float sbuf[4];
    int t = threadIdx.x;
    float v = rowval[t] + rowval[t + 256] + rowval[t + 512] + rowval[t + 768];
    #pragma unroll
    for (int s = 1; s < 64; s <<= 1) v += __shfl_xor(v, s, 64);
    if ((t & 63) == 0) sbuf[t >> 6] = v;
    __syncthreads();
    if (t == 0) out[0] = sbuf[0] + sbuf[1] + sbuf[2] + sbuf[3];
}

// ---------------------------------------------------------------------------
extern "C" void kernel_launch(void* const* d_in, const int* in_sizes, int n_in,
                              void* d_out, int out_size, void* d_ws, size_t ws_size,
                              hipStream_t stream) {
    const float* feature = (const float*)d_in[0];
    const float* weight  = (const float*)d_in[1];
    const int*   label   = (const int*)d_in[2];

    // Workspace layout (bytes):
    //   what   [0,        12812288)  : 50048*128*2
    //   fhat   [12812288, 13074432)  : 1024*128*2
    //   part2  [13074432, 14123008)  : 1024*256*4
    //   rowval [14123008, 14127104)  : 1024*4
    const size_t WS_NEEDED = 14127104;
    if (ws_size < WS_NEEDED) return;   // defensive: visible failure, not OOB writes

    char* ws = (char*)d_ws;
    unsigned short* what = (unsigned short*)ws;
    unsigned short* fhat = (unsigned short*)(ws + 12812288);
    float*         part2 = (float*)(ws + 13074432);
    float*        rowval = (float*)(ws + 14123008);

    norm_rows_fused<<<dim3(6400), 256, 0, stream>>>(weight, feature, what, fhat);
    gemm_exp_kernel<<<dim3(NG, 8), 256, 0, stream>>>((const short*)fhat, (const short*)what, part2);
    finalize_rows_kernel<<<dim3(N_ROWS / 4), 256, 0, stream>>>(part2, fhat, what, feature, weight,
                                                               label, rowval);
    reduce_final_kernel<<<1, 256, 0, stream>>>(rowval, (float*)d_out);
}